// Round 5
// baseline (5400.055 us; speedup 1.0000x reference)
//
#include <hip/hip_runtime.h>
#include <hip/hip_bf16.h>

typedef float  f32x2  __attribute__((ext_vector_type(2)));
typedef float  f32x4  __attribute__((ext_vector_type(4)));
typedef float  f32x16 __attribute__((ext_vector_type(16)));
typedef __bf16 bfrag8 __attribute__((ext_vector_type(8)));
typedef __bf16 bf16x4 __attribute__((ext_vector_type(4)));

#define T_STEPS 1024
#define BB 64
#define II 512
#define HH 512
#define G4 2048
#define NB 64
#define BH (BB*HH)   // 32768 elems

static __device__ inline unsigned short bf16_bits(float f) {
  union { __bf16 h; unsigned short u; } v; v.h = (__bf16)f; return v.u;
}
static __device__ inline float sigm(float x) { return 1.f / (1.f + __expf(-x)); }

// ---- init: slot0 = h0 (tag 0); slot1 = sentinel tag 0xFFFF ----
// Slot 1 MUST be written every call: otherwise a replay can see the previous
// replay's tag-1023 words as valid (post-timing divergence in R4).
__global__ void k_init_h(const float* __restrict__ h0, unsigned* __restrict__ hb) {
  int i = blockIdx.x * 256 + threadIdx.x;
  if (i < BH) hb[i] = ((unsigned)bf16_bits(h0[i]) << 16);     // | tag 0
  else        hb[i] = 0x0000FFFFu;                            // sentinel tag
}

// ---------------- phase 1: x_proj = input @ W_ih^T + b_ih + b_hh ----------------
template<bool XF32>
__global__ __launch_bounds__(256) void k_xproj(
    const float* __restrict__ inp, const float* __restrict__ Wih,
    const float* __restrict__ bih, const float* __restrict__ bhh,
    void* __restrict__ xp_) {
  constexpr int BM = 128, BN = 128, BK = 64, LDK = 72;
  __shared__ __bf16 As[BM][LDK];
  __shared__ __bf16 Bs[BN][LDK];
  const int bx = blockIdx.x;
  const int tm = bx >> 4, tn = bx & 15;
  const int m0 = tm * BM, n0 = tn * BN;
  const int tid = threadIdx.x;
  const int lane = tid & 63, w = tid >> 6;
  const int wm = w >> 1, wn = w & 1;
  const int l31 = lane & 31, lhi = lane >> 5;

  f32x16 acc[2][2] = {};

  const int srow = tid >> 2;
  const int sq = tid & 3;

  for (int k0 = 0; k0 < 512; k0 += BK) {
    __syncthreads();
    #pragma unroll
    for (int j = 0; j < 2; j++) {
      const int r = srow + 64 * j;
      const float* pa = inp + (size_t)(m0 + r) * II + k0 + sq * 16;
      const float* pb = Wih + (size_t)(n0 + r) * II + k0 + sq * 16;
      #pragma unroll
      for (int i = 0; i < 4; i++) {
        f32x4 va = *(const f32x4*)(pa + 4 * i);
        bf16x4 wa; wa[0]=(__bf16)va[0]; wa[1]=(__bf16)va[1]; wa[2]=(__bf16)va[2]; wa[3]=(__bf16)va[3];
        *(bf16x4*)&As[r][sq * 16 + 4 * i] = wa;
        f32x4 vb = *(const f32x4*)(pb + 4 * i);
        bf16x4 wb; wb[0]=(__bf16)vb[0]; wb[1]=(__bf16)vb[1]; wb[2]=(__bf16)vb[2]; wb[3]=(__bf16)vb[3];
        *(bf16x4*)&Bs[r][sq * 16 + 4 * i] = wb;
      }
    }
    __syncthreads();
    #pragma unroll
    for (int ks = 0; ks < 4; ks++) {
      const int kk = ks * 16 + 8 * lhi;
      bfrag8 af0 = *(const bfrag8*)&As[64 * wm +      l31][kk];
      bfrag8 af1 = *(const bfrag8*)&As[64 * wm + 32 + l31][kk];
      bfrag8 bf0 = *(const bfrag8*)&Bs[64 * wn +      l31][kk];
      bfrag8 bf1 = *(const bfrag8*)&Bs[64 * wn + 32 + l31][kk];
      acc[0][0] = __builtin_amdgcn_mfma_f32_32x32x16_bf16(af0, bf0, acc[0][0], 0, 0, 0);
      acc[0][1] = __builtin_amdgcn_mfma_f32_32x32x16_bf16(af0, bf1, acc[0][1], 0, 0, 0);
      acc[1][0] = __builtin_amdgcn_mfma_f32_32x32x16_bf16(af1, bf0, acc[1][0], 0, 0, 0);
      acc[1][1] = __builtin_amdgcn_mfma_f32_32x32x16_bf16(af1, bf1, acc[1][1], 0, 0, 0);
    }
  }
  #pragma unroll
  for (int a = 0; a < 2; a++)
    #pragma unroll
    for (int b = 0; b < 2; b++) {
      const int col = n0 + 64 * wn + 32 * b + l31;
      const float bias = bih[col] + bhh[col];
      #pragma unroll
      for (int q = 0; q < 16; q++) {
        const int row = m0 + 64 * wm + 32 * a + (q & 3) + 8 * (q >> 2) + 4 * lhi;
        const float v = acc[a][b][q] + bias;
        if constexpr (XF32) ((float*)xp_)[(size_t)row * G4 + col] = v;
        else                ((__bf16*)xp_)[(size_t)row * G4 + col] = (__bf16)v;
      }
    }
}

// ---------------- phase 2: persistent recurrence, data-as-flag ----------------
// h exchanged as tagged u32 words: (bf16_bits << 16) | step_tag.
// Poll = concurrent partial-resweep: each sweep re-issues ALL still-missing
// words together (one IC round-trip per sweep, no serial per-word spins).
// xv (x_proj) is software-pipelined one step ahead so the detect path never
// waits on HBM.
template<bool XF32>
__global__ __launch_bounds__(256, 1) void k_recur(
    const float* __restrict__ Whh, const float* __restrict__ c0,
    const void* __restrict__ xp_, unsigned* __restrict__ hb,
    float* __restrict__ out) {
  const int bid = blockIdx.x;
  const int rb = bid & 1;
  const int g  = bid >> 1;
  const int tid = threadIdx.x;
  const int lane = tid & 63, w = tid >> 6;
  const int tt = w & 1, kh = w >> 1;
  const int l31 = lane & 31, lhi = lane >> 5;

  __shared__ __bf16 hA[32][520];        // 32 rows x 512 K, +16B pad
  __shared__ float pS[2][2][32][33];    // [kh][tt][row][col31], +1 pad

  const int gate = tt * 2 + (l31 >> 4);               // 0..3 (i,f,z,o)
  const int gcol = gate * 512 + g * 16 + (l31 & 15);  // global gate column

  // W_hh fragments once: B-operand layout col=lane&31, k = 8*(lane>>5)+j
  bfrag8 bw[16];
  #pragma unroll
  for (int ks = 0; ks < 16; ks++) {
    const float* p = Whh + (size_t)gcol * HH + kh * 256 + ks * 16 + 8 * lhi;
    f32x4 v0 = *(const f32x4*)p;
    f32x4 v1 = *(const f32x4*)(p + 4);
    bfrag8 f;
    f[0]=(__bf16)v0[0]; f[1]=(__bf16)v0[1]; f[2]=(__bf16)v0[2]; f[3]=(__bf16)v0[3];
    f[4]=(__bf16)v1[0]; f[5]=(__bf16)v1[1]; f[6]=(__bf16)v1[2]; f[7]=(__bf16)v1[3];
    bw[ks] = f;
  }

  // c ownership: thread owns row lb = tid>>3, adjacent cols c2, c2+1
  const int lb = tid >> 3, c2 = (tid & 7) * 2;
  const int brow = 32 * rb + lb;        // global batch row
  const int jcol = 16 * g + c2;         // global h col (even)
  f32x2 creg = *(const f32x2*)(c0 + (size_t)brow * HH + jcol);

  const int str = w * 8 + (lane >> 3);  // staging row 0..31
  const int sb  = lane & 7;             // u64 chunk id within row (8 threads/row)

  // xv pipeline rows (kh0 waves): row offsets within the 32-row batch half
  int xrow[16];
  #pragma unroll
  for (int q = 0; q < 16; q++) xrow[q] = (q & 3) + 8 * (q >> 2) + 4 * lhi;

  // ---- prologue: prefetch xv for s = 0 (t = T-1) ----
  f32x16 xv_cur = {}, xv_nxt = {};
  if (kh == 0) {
    #pragma unroll
    for (int q = 0; q < 16; q++) {
      const size_t idx = ((size_t)(T_STEPS - 1) * BB + 32 * rb + xrow[q]) * G4 + gcol;
      if constexpr (XF32) xv_cur[q] = ((const float*)xp_)[idx];
      else                xv_cur[q] = (float)((const __bf16*)xp_)[idx];
    }
  }

  for (int s = 0; s < T_STEPS; s++) {
    const int t = T_STEPS - 1 - s;

    // ---- poll + load: concurrent partial-resweep on tagged words ----
    const unsigned long long* hrow = (const unsigned long long*)
        (hb + (size_t)(s & 1) * BH + (size_t)(32 * rb + str) * HH);
    const unsigned long long tpat = 0x0000FFFF0000FFFFull;
    const unsigned long long texp = (unsigned long long)s * 0x0000000100000001ull;
    unsigned long long v[32];
    unsigned need = 0xFFFFFFFFu;
    for (;;) {
      #pragma unroll
      for (int i = 0; i < 32; i++)
        if (need & (1u << i))
          v[i] = __hip_atomic_load(hrow + sb + 8 * i,
                                   __ATOMIC_RELAXED, __HIP_MEMORY_SCOPE_AGENT);
      unsigned miss = 0;
      #pragma unroll
      for (int i = 0; i < 32; i++)
        if ((need & (1u << i)) && ((v[i] & tpat) != texp)) miss |= 1u << i;
      if (miss == 0) break;
      need = miss;
    }
    // Extract bf16 pairs (hi16 of each u32) -> LDS
    #pragma unroll
    for (int i = 0; i < 32; i++) {
      const unsigned lo = (unsigned)v[i], hi = (unsigned)(v[i] >> 32);
      const unsigned packed = (lo >> 16) | (hi & 0xFFFF0000u);
      *(unsigned*)&hA[str][(sb + 8 * i) * 2] = packed;
    }

    // ---- prefetch xv for s+1 (in flight across MFMA + barriers) ----
    if (kh == 0 && s + 1 < T_STEPS) {
      #pragma unroll
      for (int q = 0; q < 16; q++) {
        const size_t idx = ((size_t)(t - 1) * BB + 32 * rb + xrow[q]) * G4 + gcol;
        if constexpr (XF32) xv_nxt[q] = ((const float*)xp_)[idx];
        else                xv_nxt[q] = (float)((const __bf16*)xp_)[idx];
      }
    }
    __syncthreads();

    // ---- GEMM: this wave's 32x32 tile, K = its 256-half ----
    f32x16 acc = {};
    #pragma unroll
    for (int ks = 0; ks < 16; ks++) {
      bfrag8 a = *(const bfrag8*)&hA[l31][kh * 256 + ks * 16 + 8 * lhi];
      acc = __builtin_amdgcn_mfma_f32_32x32x16_bf16(a, bw[ks], acc, 0, 0, 0);
    }
    // ---- single exchange: raw partials (kh0 adds xv_cur) ----
    #pragma unroll
    for (int q = 0; q < 16; q++) {
      const int row = (q & 3) + 8 * (q >> 2) + 4 * lhi;
      pS[kh][tt][row][l31] = (kh == 0) ? (acc[q] + xv_cur[q]) : acc[q];
    }
    __syncthreads();

    // ---- gates + c/h update, per owner thread (lb, c2..c2+1) ----
    {
      float sg[4][2];
      #pragma unroll
      for (int gt = 0; gt < 4; gt++) {
        const int tl = gt >> 1, off = (gt & 1) * 16;
        #pragma unroll
        for (int dc = 0; dc < 2; dc++) {
          const int col = off + c2 + dc;
          sg[gt][dc] = sigm(pS[0][tl][lb][col] + pS[1][tl][lb][col]);
        }
      }
      const float cn0 = sg[1][0] * creg[0] + sg[2][0] - sg[0][0];
      const float cn1 = sg[1][1] * creg[1] + sg[2][1] - sg[0][1];
      creg[0] = cn0; creg[1] = cn1;
      const float hn0 = sigm(cn0) - sg[3][0];
      const float hn1 = sigm(cn1) - sg[3][1];
      // tagged h broadcast FIRST (critical path), HBM out after
      const unsigned tag = (unsigned)(s + 1);
      const unsigned plo = ((unsigned)bf16_bits(hn0) << 16) | tag;
      const unsigned phi = ((unsigned)bf16_bits(hn1) << 16) | tag;
      const unsigned long long pv = ((unsigned long long)phi << 32) | plo;
      __hip_atomic_store((unsigned long long*)
          (hb + (size_t)((s + 1) & 1) * BH + (size_t)brow * HH + jcol),
          pv, __ATOMIC_RELAXED, __HIP_MEMORY_SCOPE_AGENT);
      f32x2 hv; hv[0] = hn0; hv[1] = hn1;
      __builtin_nontemporal_store(hv,
          (f32x2*)(out + (size_t)t * BH + (size_t)brow * HH + jcol));
      if (s == T_STEPS - 1) {
        f32x2 cv; cv[0] = cn0; cv[1] = cn1;
        *(f32x2*)(out + (size_t)T_STEPS * BH + (size_t)brow * HH + jcol) = hv;       // h_f
        *(f32x2*)(out + (size_t)T_STEPS * BH + BH + (size_t)brow * HH + jcol) = cv;  // c_f
      }
    }
    xv_cur = xv_nxt;
    // No drain, no flag, no trailing barrier.
  }
}

extern "C" void kernel_launch(void* const* d_in, const int* in_sizes, int n_in,
                              void* d_out, int out_size, void* d_ws, size_t ws_size,
                              hipStream_t stream) {
  (void)in_sizes; (void)n_in; (void)out_size;
  const float* inp = (const float*)d_in[0];
  const float* h0  = (const float*)d_in[1];
  const float* c0  = (const float*)d_in[2];
  const float* Wih = (const float*)d_in[3];
  const float* Whh = (const float*)d_in[4];
  const float* bih = (const float*)d_in[5];
  const float* bhh = (const float*)d_in[6];
  float* out = (float*)d_out;
  char* ws = (char*)d_ws;

  // ws layout: hb (2-slot tagged u32, 256 KB) @0 | x_proj @1MB
  unsigned* hb = (unsigned*)ws;
  void*     xp = (void*)(ws + (1u << 20));
  const size_t need_f32 = (1u << 20) + (size_t)T_STEPS * BB * G4 * 4;
  const bool xf32 = ws_size >= need_f32;

  k_init_h<<<2 * BH / 256, 256, 0, stream>>>(h0, hb);   // both slots
  const int gemm_grid = (T_STEPS * BB / 128) * (G4 / 128);  // 8192
  if (xf32) {
    k_xproj<true ><<<gemm_grid, 256, 0, stream>>>(inp, Wih, bih, bhh, xp);
    k_recur<true ><<<NB, 256, 0, stream>>>(Whh, c0, xp, hb, out);
  } else {
    k_xproj<false><<<gemm_grid, 256, 0, stream>>>(inp, Wih, bih, bhh, xp);
    k_recur<false><<<NB, 256, 0, stream>>>(Whh, c0, xp, hb, out);
  }
}

// Round 6
// 4709.615 us; speedup vs baseline: 1.1466x; 1.1466x over previous
//
#include <hip/hip_runtime.h>
#include <hip/hip_bf16.h>

typedef float  f32x2  __attribute__((ext_vector_type(2)));
typedef float  f32x4  __attribute__((ext_vector_type(4)));
typedef float  f32x16 __attribute__((ext_vector_type(16)));
typedef __bf16 bfrag8 __attribute__((ext_vector_type(8)));
typedef __bf16 bf16x4 __attribute__((ext_vector_type(4)));
typedef int    i32x4  __attribute__((ext_vector_type(4)));

#define T_STEPS 1024
#define BB 64
#define II 512
#define HH 512
#define G4 2048
#define NB 64
#define BH (BB*HH)   // 32768 elems per h slot

static __device__ inline unsigned short bf16_bits(float f) {
  union { __bf16 h; unsigned short u; } v; v.h = (__bf16)f; return v.u;
}
static __device__ inline float sigm(float x) { return 1.f / (1.f + __expf(-x)); }

// ---- init: h slot0 = h0 (plain bf16); stamps zeroed (replay-safe) ----
__global__ void k_init_h(const float* __restrict__ h0, __bf16* __restrict__ hb,
                         unsigned* __restrict__ stamps) {
  int i = blockIdx.x * 256 + threadIdx.x;
  hb[i] = (__bf16)h0[i];
  if (blockIdx.x == 0 && threadIdx.x < NB) stamps[threadIdx.x] = 0u;
}

// ---------------- phase 1: x_proj = input @ W_ih^T + b_ih + b_hh ----------------
template<bool XF32>
__global__ __launch_bounds__(256) void k_xproj(
    const float* __restrict__ inp, const float* __restrict__ Wih,
    const float* __restrict__ bih, const float* __restrict__ bhh,
    void* __restrict__ xp_) {
  constexpr int BM = 128, BN = 128, BK = 64, LDK = 72;
  __shared__ __bf16 As[BM][LDK];
  __shared__ __bf16 Bs[BN][LDK];
  const int bx = blockIdx.x;
  const int tm = bx >> 4, tn = bx & 15;
  const int m0 = tm * BM, n0 = tn * BN;
  const int tid = threadIdx.x;
  const int lane = tid & 63, w = tid >> 6;
  const int wm = w >> 1, wn = w & 1;
  const int l31 = lane & 31, lhi = lane >> 5;

  f32x16 acc[2][2] = {};
  const int srow = tid >> 2;
  const int sq = tid & 3;

  for (int k0 = 0; k0 < 512; k0 += BK) {
    __syncthreads();
    #pragma unroll
    for (int j = 0; j < 2; j++) {
      const int r = srow + 64 * j;
      const float* pa = inp + (size_t)(m0 + r) * II + k0 + sq * 16;
      const float* pb = Wih + (size_t)(n0 + r) * II + k0 + sq * 16;
      #pragma unroll
      for (int i = 0; i < 4; i++) {
        f32x4 va = *(const f32x4*)(pa + 4 * i);
        bf16x4 wa; wa[0]=(__bf16)va[0]; wa[1]=(__bf16)va[1]; wa[2]=(__bf16)va[2]; wa[3]=(__bf16)va[3];
        *(bf16x4*)&As[r][sq * 16 + 4 * i] = wa;
        f32x4 vb = *(const f32x4*)(pb + 4 * i);
        bf16x4 wb; wb[0]=(__bf16)vb[0]; wb[1]=(__bf16)vb[1]; wb[2]=(__bf16)vb[2]; wb[3]=(__bf16)vb[3];
        *(bf16x4*)&Bs[r][sq * 16 + 4 * i] = wb;
      }
    }
    __syncthreads();
    #pragma unroll
    for (int ks = 0; ks < 4; ks++) {
      const int kk = ks * 16 + 8 * lhi;
      bfrag8 af0 = *(const bfrag8*)&As[64 * wm +      l31][kk];
      bfrag8 af1 = *(const bfrag8*)&As[64 * wm + 32 + l31][kk];
      bfrag8 bf0 = *(const bfrag8*)&Bs[64 * wn +      l31][kk];
      bfrag8 bf1 = *(const bfrag8*)&Bs[64 * wn + 32 + l31][kk];
      acc[0][0] = __builtin_amdgcn_mfma_f32_32x32x16_bf16(af0, bf0, acc[0][0], 0, 0, 0);
      acc[0][1] = __builtin_amdgcn_mfma_f32_32x32x16_bf16(af0, bf1, acc[0][1], 0, 0, 0);
      acc[1][0] = __builtin_amdgcn_mfma_f32_32x32x16_bf16(af1, bf0, acc[1][0], 0, 0, 0);
      acc[1][1] = __builtin_amdgcn_mfma_f32_32x32x16_bf16(af1, bf1, acc[1][1], 0, 0, 0);
    }
  }
  #pragma unroll
  for (int a = 0; a < 2; a++)
    #pragma unroll
    for (int b = 0; b < 2; b++) {
      const int col = n0 + 64 * wn + 32 * b + l31;
      const float bias = bih[col] + bhh[col];
      #pragma unroll
      for (int q = 0; q < 16; q++) {
        const int row = m0 + 64 * wm + 32 * a + (q & 3) + 8 * (q >> 2) + 4 * lhi;
        const float v = acc[a][b][q] + bias;
        if constexpr (XF32) ((float*)xp_)[(size_t)row * G4 + col] = v;
        else                ((__bf16*)xp_)[(size_t)row * G4 + col] = (__bf16)v;
      }
    }
}

// ---------------- phase 2: persistent recurrence, stamp-gated exchange -------
// Producer: h stores (sc1) -> per-thread vmcnt(0) -> barrier -> tid0 stamps
// stamps[bid]=s+1 (monotonic). Consumer: wave0 polls the 32 stamps of its
// half (8 KB/sweep total, no fabric saturation), barrier, then ONE bulk pass
// of h via global_load_dwordx4 sc0 sc1. Raw s_barrier everywhere (no implicit
// vmcnt(0)) so the xv prefetch survives across MFMA/pS/gates.
template<bool XF32>
__global__ __launch_bounds__(256, 1) void k_recur(
    const float* __restrict__ Whh, const float* __restrict__ c0,
    const void* __restrict__ xp_, __bf16* __restrict__ hb,
    unsigned* __restrict__ stamps, float* __restrict__ out) {
  const int bid = blockIdx.x;
  const int rb = bid & 1;
  const int g  = bid >> 1;
  const int tid = threadIdx.x;
  const int lane = tid & 63, w = tid >> 6;
  const int tt = w & 1, kh = w >> 1;
  const int l31 = lane & 31, lhi = lane >> 5;

  __shared__ __bf16 hA[32][520];        // 32 rows x 512 K, +16B pad
  __shared__ float pS[2][2][32][33];    // [kh][tt][row][col31], +1 pad

  const int gate = tt * 2 + (l31 >> 4);               // 0..3 (i,f,z,o)
  const int gcol = gate * 512 + g * 16 + (l31 & 15);  // global gate column

  // W_hh fragments once: B-operand layout col=lane&31, k = 8*(lane>>5)+j
  bfrag8 bw[16];
  #pragma unroll
  for (int ks = 0; ks < 16; ks++) {
    const float* p = Whh + (size_t)gcol * HH + kh * 256 + ks * 16 + 8 * lhi;
    f32x4 v0 = *(const f32x4*)p;
    f32x4 v1 = *(const f32x4*)(p + 4);
    bfrag8 f;
    f[0]=(__bf16)v0[0]; f[1]=(__bf16)v0[1]; f[2]=(__bf16)v0[2]; f[3]=(__bf16)v0[3];
    f[4]=(__bf16)v1[0]; f[5]=(__bf16)v1[1]; f[6]=(__bf16)v1[2]; f[7]=(__bf16)v1[3];
    bw[ks] = f;
  }

  // c ownership: thread owns row lb = tid>>3, adjacent cols c2, c2+1
  const int lb = tid >> 3, c2 = (tid & 7) * 2;
  const int brow = 32 * rb + lb;
  const int jcol = 16 * g + c2;
  f32x2 creg = *(const f32x2*)(c0 + (size_t)brow * HH + jcol);

  const int str = w * 8 + (lane >> 3);  // staging row 0..31
  const int sb  = lane & 7;             // 16B chunk id within 128B group

  int xrow[16];
  #pragma unroll
  for (int q = 0; q < 16; q++) xrow[q] = (q & 3) + 8 * (q >> 2) + 4 * lhi;

  // prologue: xv for s=0 (t=T-1); completes long before first use
  f32x16 xv_cur = {}, xv_nxt = {};
  if (kh == 0) {
    #pragma unroll
    for (int q = 0; q < 16; q++) {
      const size_t idx = ((size_t)(T_STEPS - 1) * BB + 32 * rb + xrow[q]) * G4 + gcol;
      if constexpr (XF32) xv_cur[q] = ((const float*)xp_)[idx];
      else                xv_cur[q] = (float)((const __bf16*)xp_)[idx];
    }
  }

  const unsigned* mystamp = stamps + 2 * l31 + rb;   // lane<32: producer g'=l31

  for (int s = 0; s < T_STEPS; s++) {
    const int t = T_STEPS - 1 - s;

    // ---- wave0-only stamp poll (tiny traffic) ----
    if (w == 0 && s > 0) {
      for (;;) {
        unsigned st = (lane < 32)
            ? __hip_atomic_load(mystamp, __ATOMIC_RELAXED, __HIP_MEMORY_SCOPE_AGENT)
            : 0xFFFFFFFFu;
        if (__all((int)(st >= (unsigned)s))) break;
      }
    }
    __builtin_amdgcn_s_barrier();            // poll-bar
    asm volatile("" ::: "memory");

    // ---- bulk h read: 8 x 16B agent-coherent loads (bypass L1/L2) ----
    const char* hbase = (const char*)hb
        + (size_t)(s & 1) * (BH * 2)
        + ((size_t)(32 * rb + str) * HH + sb * 8) * 2;
    i32x4 hv[8];
    #pragma unroll
    for (int i = 0; i < 8; i++) {
      unsigned long long a64 = (unsigned long long)(hbase + i * 128);
      asm volatile("global_load_dwordx4 %0, %1, off sc0 sc1"
                   : "=v"(hv[i]) : "v"(a64));
    }
    asm volatile("s_waitcnt vmcnt(0)" ::: "memory");
    #pragma unroll
    for (int i = 0; i < 8; i++)
      *(i32x4*)&hA[str][sb * 8 + i * 64] = hv[i];

    // ---- xv prefetch for s+1: stays in flight across MFMA/pS/gates ----
    if (kh == 0 && s + 1 < T_STEPS) {
      #pragma unroll
      for (int q = 0; q < 16; q++) {
        const size_t idx = ((size_t)(t - 1) * BB + 32 * rb + xrow[q]) * G4 + gcol;
        if constexpr (XF32) xv_nxt[q] = ((const float*)xp_)[idx];
        else                xv_nxt[q] = (float)((const __bf16*)xp_)[idx];
      }
    }
    asm volatile("s_waitcnt lgkmcnt(0)" ::: "memory");
    __builtin_amdgcn_s_barrier();            // stage-bar
    asm volatile("" ::: "memory");

    // ---- GEMM: acc initialized with xv (kh0) so no later xv add needed ----
    f32x16 acc;
    #pragma unroll
    for (int q = 0; q < 16; q++) acc[q] = (kh == 0) ? xv_cur[q] : 0.f;
    #pragma unroll
    for (int ks = 0; ks < 16; ks++) {
      bfrag8 a = *(const bfrag8*)&hA[l31][kh * 256 + ks * 16 + 8 * lhi];
      acc = __builtin_amdgcn_mfma_f32_32x32x16_bf16(a, bw[ks], acc, 0, 0, 0);
    }
    #pragma unroll
    for (int q = 0; q < 16; q++) {
      const int row = (q & 3) + 8 * (q >> 2) + 4 * lhi;
      pS[kh][tt][row][l31] = acc[q];
    }
    asm volatile("s_waitcnt lgkmcnt(0)" ::: "memory");
    __builtin_amdgcn_s_barrier();            // pS-bar
    asm volatile("" ::: "memory");

    // ---- gates + c/h update ----
    float cn0, cn1, hn0, hn1;
    {
      float sg[4][2];
      #pragma unroll
      for (int gt = 0; gt < 4; gt++) {
        const int tl = gt >> 1, off = (gt & 1) * 16;
        #pragma unroll
        for (int dc = 0; dc < 2; dc++) {
          const int col = off + c2 + dc;
          sg[gt][dc] = sigm(pS[0][tl][lb][col] + pS[1][tl][lb][col]);
        }
      }
      cn0 = sg[1][0] * creg[0] + sg[2][0] - sg[0][0];
      cn1 = sg[1][1] * creg[1] + sg[2][1] - sg[0][1];
      creg[0] = cn0; creg[1] = cn1;
      hn0 = sigm(cn0) - sg[3][0];
      hn1 = sigm(cn1) - sg[3][1];
      // h broadcast (agent-scope, IC)
      const unsigned pk = ((unsigned)bf16_bits(hn0)) | ((unsigned)bf16_bits(hn1) << 16);
      __hip_atomic_store((unsigned*)
          (hb + (size_t)((s + 1) & 1) * BH + (size_t)brow * HH + jcol),
          pk, __ATOMIC_RELAXED, __HIP_MEMORY_SCOPE_AGENT);
    }
    // drain h stores (xv_nxt rides along; its latency is shared with this wait)
    asm volatile("s_waitcnt vmcnt(0)" ::: "memory");
    __builtin_amdgcn_s_barrier();            // drain-bar
    asm volatile("" ::: "memory");
    if (tid == 0)
      __hip_atomic_store(stamps + bid, (unsigned)(s + 1),
                         __ATOMIC_RELAXED, __HIP_MEMORY_SCOPE_AGENT);

    // out stores off the critical path (after stamping)
    f32x2 hvv; hvv[0] = hn0; hvv[1] = hn1;
    __builtin_nontemporal_store(hvv,
        (f32x2*)(out + (size_t)t * BH + (size_t)brow * HH + jcol));
    if (s == T_STEPS - 1) {
      f32x2 cv; cv[0] = cn0; cv[1] = cn1;
      *(f32x2*)(out + (size_t)T_STEPS * BH + (size_t)brow * HH + jcol) = hvv;      // h_f
      *(f32x2*)(out + (size_t)T_STEPS * BH + BH + (size_t)brow * HH + jcol) = cv;  // c_f
    }
    xv_cur = xv_nxt;
  }
}

extern "C" void kernel_launch(void* const* d_in, const int* in_sizes, int n_in,
                              void* d_out, int out_size, void* d_ws, size_t ws_size,
                              hipStream_t stream) {
  (void)in_sizes; (void)n_in; (void)out_size;
  const float* inp = (const float*)d_in[0];
  const float* h0  = (const float*)d_in[1];
  const float* c0  = (const float*)d_in[2];
  const float* Wih = (const float*)d_in[3];
  const float* Whh = (const float*)d_in[4];
  const float* bih = (const float*)d_in[5];
  const float* bhh = (const float*)d_in[6];
  float* out = (float*)d_out;
  char* ws = (char*)d_ws;

  // ws layout: stamps @0 (256B) | hb (2 slots plain bf16, 128KB) @4KB | x_proj @1MB
  unsigned* stamps = (unsigned*)ws;
  __bf16*   hb     = (__bf16*)(ws + 4096);
  void*     xp     = (void*)(ws + (1u << 20));
  const size_t need_f32 = (1u << 20) + (size_t)T_STEPS * BB * G4 * 4;
  const bool xf32 = ws_size >= need_f32;

  k_init_h<<<BH / 256, 256, 0, stream>>>(h0, hb, stamps);
  const int gemm_grid = (T_STEPS * BB / 128) * (G4 / 128);  // 8192
  if (xf32) {
    k_xproj<true ><<<gemm_grid, 256, 0, stream>>>(inp, Wih, bih, bhh, xp);
    k_recur<true ><<<NB, 256, 0, stream>>>(Whh, c0, xp, hb, stamps, out);
  } else {
    k_xproj<false><<<gemm_grid, 256, 0, stream>>>(inp, Wih, bih, bhh, xp);
    k_recur<false><<<NB, 256, 0, stream>>>(Whh, c0, xp, hb, stamps, out);
  }
}